// Round 1
// baseline (1060.589 us; speedup 1.0000x reference)
//
#include <hip/hip_runtime.h>

#define SQRT2F 1.41421356237309515f

typedef __attribute__((ext_vector_type(8))) short short8;
typedef __attribute__((ext_vector_type(4))) float floatx4;

static __device__ __forceinline__ unsigned short f2bf(float f) {
    unsigned int u = __float_as_uint(f);
    u += 0x7fffu + ((u >> 16) & 1u);   // RNE
    return (unsigned short)(u >> 16);
}

// ---------------- kernel 1: style = lrelu(latent @ (aw/sqrt(512)).T + abias)*sqrt2 ----
__global__ void style_kernel(const float* __restrict__ latent,
                             const float* __restrict__ aw,
                             const float* __restrict__ abias,
                             float* __restrict__ style) {
    const int b = blockIdx.x;
    const int t = threadIdx.x;              // 256
    __shared__ float lat[512];
    lat[t]       = latent[b * 512 + t];
    lat[t + 256] = latent[b * 512 + t + 256];
    __syncthreads();
    const float wmul = 0.04419417382415922f;  // 1/sqrt(512)
    for (int c = t; c < 512; c += 256) {
        const float* row = aw + (size_t)c * 512;
        float s = 0.f;
        #pragma unroll 8
        for (int k = 0; k < 512; ++k) s += lat[k] * row[k];
        s = s * wmul + abias[c];
        s = (s > 0.f ? s : 0.2f * s) * SQRT2F;
        style[b * 512 + c] = s;
    }
}

// ---------------- kernel 2: demod + modulated bf16 weights, layout [b][tap][co][cin] ----
__global__ void wmod_kernel(const float* __restrict__ cw,
                            const float* __restrict__ style,
                            unsigned short* __restrict__ wmod) {
    const int co = blockIdx.x;
    const int b  = blockIdx.y;
    const int t  = threadIdx.x;             // 256
    __shared__ float sty[512];
    __shared__ float red[8];
    sty[t]       = style[b * 512 + t];
    sty[t + 256] = style[b * 512 + t + 256];
    __syncthreads();
    const float* row = cw + (size_t)co * 4608;   // [cin][3][3] flat: cin*9+tap
    float s = 0.f;
    for (int idx = t; idx < 4608; idx += 256) {
        int cin = idx / 9;
        float v = row[idx] * sty[cin];
        s += v * v;
    }
    #pragma unroll
    for (int off = 32; off > 0; off >>= 1) s += __shfl_down(s, off, 64);
    const int lane = t & 63, wv = t >> 6;
    if (lane == 0) red[wv] = s;
    __syncthreads();
    if (t == 0) red[0] = rsqrtf(red[0] + red[1] + red[2] + red[3] + 1e-8f);
    __syncthreads();
    const float dm = red[0];
    for (int oidx = t; oidx < 4608; oidx += 256) {
        int tap = oidx >> 9, cin = oidx & 511;
        float v = row[cin * 9 + tap] * sty[cin] * dm;
        wmod[(((size_t)b * 9 + tap) * 512 + co) * 512 + cin] = f2bf(v);
    }
}

// ---------------- kernel 3: implicit-GEMM modulated conv, bf16 MFMA ----------------
// D[co][pix] per sample; 128x128 tile; pix tile = 8 rows x 16 cols.
// K-loop: 16 cin-slabs of 32, x 9 taps (shifted reads of the x halo tile in LDS).
__launch_bounds__(256)
__global__ void conv_kernel(const float* __restrict__ x,
                            const float* __restrict__ noise,
                            const float* __restrict__ nwp,
                            const float* __restrict__ bias,
                            const unsigned short* __restrict__ wmod,
                            float* __restrict__ out) {
    const int b   = blockIdx.z;
    const int co0 = blockIdx.y * 128;
    const int tr  = blockIdx.x >> 2, tc = blockIdx.x & 3;
    const int h0  = tr * 8, w0 = tc * 16;
    const int tid  = threadIdx.x;
    const int lane = tid & 63, wv = tid >> 6;
    const int wr = wv >> 1, wc = wv & 1;
    const int quad = lane >> 4, l16 = lane & 15;

    __shared__ unsigned short lds_x[10 * 18 * 40];    // [row0..9][col0..17][cin pad40] 14.4 KB
    __shared__ unsigned short lds_w[2][128 * 40];     // ping-pong [co][cin pad40]     20.5 KB

    floatx4 acc[4][4] = {};

    const float  nw = nwp[0];
    const float* nz = noise + (size_t)b * 4096;

    // staging maps
    const int sx_ci = tid >> 3;            // 0..31 cin-in-slab
    const int sx_c0 = tid & 7;             // col phase
    const int sw_co = tid >> 1;            // 0..127
    const int sw_ci = (tid & 1) << 4;      // 0 or 16

    // A-frag LDS element offsets (constant): W[co=wr*64+mi*16+l16][k=quad*8+j]
    int a_off[4];
    #pragma unroll
    for (int mi = 0; mi < 4; ++mi) a_off[mi] = (wr * 64 + mi * 16 + l16) * 40 + quad * 8;
    // B-frag base offsets: X[(row=wc*4+ni)+kh][(col=l16)+kw][k=quad*8+j]
    int b_base[4];
    #pragma unroll
    for (int ni = 0; ni < 4; ++ni) b_base[ni] = ((wc * 4 + ni) * 18 + l16) * 40 + quad * 8;
    const int TAPOFF[9] = {0, 40, 80, 720, 760, 800, 1440, 1480, 1520}; // (kh*18+kw)*40

    for (int slab = 0; slab < 16; ++slab) {
        // ---- stage x halo tile (adds noise, converts to bf16, transposed [pos][cin]) ----
        {
            const float* xb = x + ((size_t)(b * 512 + slab * 32 + sx_ci)) * 4096;
            #pragma unroll
            for (int r = 0; r < 10; ++r) {
                const int gh = h0 + r - 1;
                const bool hv = ((unsigned)gh < 64u);
                #pragma unroll
                for (int cc = 0; cc < 3; ++cc) {
                    const int c = sx_c0 + cc * 8;
                    if (c < 18) {
                        const int gw = w0 + c - 1;
                        float v = 0.f;
                        if (hv && (unsigned)gw < 64u)
                            v = xb[gh * 64 + gw] + nw * nz[gh * 64 + gw];
                        lds_x[(r * 18 + c) * 40 + sx_ci] = f2bf(v);
                    }
                }
            }
        }
        // ---- stage W(tap 0) into buf 0 ----
        {
            const size_t g = ((((size_t)b * 9 + 0) * 512 + co0 + sw_co) << 9)
                             + (size_t)(slab * 32 + sw_ci);
            const int4* src = (const int4*)(wmod + g);
            int4* dst = (int4*)&lds_w[0][sw_co * 40 + sw_ci];
            dst[0] = src[0];
            dst[1] = src[1];
        }
        __syncthreads();

        #pragma unroll
        for (int tap = 0; tap < 9; ++tap) {
            if (tap < 8) {   // prefetch next tap into the other buffer
                const size_t g = ((((size_t)b * 9 + (tap + 1)) * 512 + co0 + sw_co) << 9)
                                 + (size_t)(slab * 32 + sw_ci);
                const int4* src = (const int4*)(wmod + g);
                int4* dst = (int4*)&lds_w[(tap + 1) & 1][sw_co * 40 + sw_ci];
                dst[0] = src[0];
                dst[1] = src[1];
            }
            {
                const unsigned short* wb = lds_w[tap & 1];
                short8 a[4], bb[4];
                #pragma unroll
                for (int mi = 0; mi < 4; ++mi)
                    a[mi] = *(const short8*)(wb + a_off[mi]);
                const int toff = TAPOFF[tap];
                #pragma unroll
                for (int ni = 0; ni < 4; ++ni)
                    bb[ni] = *(const short8*)(lds_x + b_base[ni] + toff);
                #pragma unroll
                for (int mi = 0; mi < 4; ++mi)
                    #pragma unroll
                    for (int ni = 0; ni < 4; ++ni)
                        acc[mi][ni] = __builtin_amdgcn_mfma_f32_16x16x32_bf16(
                            a[mi], bb[ni], acc[mi][ni], 0, 0, 0);
            }
            __syncthreads();
        }
    }

    // ---- epilogue: bias + leaky_relu*sqrt2, coalesced stores ----
    #pragma unroll
    for (int mi = 0; mi < 4; ++mi) {
        const int cob = co0 + wr * 64 + mi * 16 + quad * 4;
        float bv[4];
        #pragma unroll
        for (int i = 0; i < 4; ++i) bv[i] = bias[cob + i];
        #pragma unroll
        for (int ni = 0; ni < 4; ++ni) {
            const int gh = h0 + wc * 4 + ni;
            const int gw = w0 + l16;
            #pragma unroll
            for (int i = 0; i < 4; ++i) {
                float v = acc[mi][ni][i] + bv[i];
                v = (v > 0.f ? v : 0.2f * v) * SQRT2F;
                out[(((size_t)b * 512 + cob + i) * 64 + gh) * 64 + gw] = v;
            }
        }
    }
}

extern "C" void kernel_launch(void* const* d_in, const int* in_sizes, int n_in,
                              void* d_out, int out_size, void* d_ws, size_t ws_size,
                              hipStream_t stream) {
    const float* x      = (const float*)d_in[0];
    const float* latent = (const float*)d_in[1];
    const float* noise  = (const float*)d_in[2];
    const float* aw     = (const float*)d_in[3];
    const float* abias  = (const float*)d_in[4];
    const float* cw     = (const float*)d_in[5];
    const float* nwp    = (const float*)d_in[6];
    const float* bias   = (const float*)d_in[7];
    float* out = (float*)d_out;

    float* style         = (float*)d_ws;                            // 32 KB
    unsigned short* wmod = (unsigned short*)((char*)d_ws + 65536);  // 75.5 MB

    style_kernel<<<dim3(16), dim3(256), 0, stream>>>(latent, aw, abias, style);
    wmod_kernel<<<dim3(512, 16), dim3(256), 0, stream>>>(cw, style, wmod);
    conv_kernel<<<dim3(32, 4, 16), dim3(256), 0, stream>>>(x, noise, nwp, bias, wmod, out);
}

// Round 3
// 555.111 us; speedup vs baseline: 1.9106x; 1.9106x over previous
//
#include <hip/hip_runtime.h>

#define SQRT2F 1.41421356237309515f

typedef __attribute__((ext_vector_type(8))) short short8;
typedef __attribute__((ext_vector_type(4))) float floatx4;

static __device__ __forceinline__ unsigned short f2bf(float f) {
    unsigned int u = __float_as_uint(f);
    u += 0x7fffu + ((u >> 16) & 1u);   // RNE
    return (unsigned short)(u >> 16);
}

static __device__ __forceinline__ void gl_lds16(const void* g, void* l) {
    __builtin_amdgcn_global_load_lds(
        (const __attribute__((address_space(1))) unsigned int*)g,
        (__attribute__((address_space(3))) unsigned int*)l, 16, 0, 0);
}

// ---------------- kernel 1: style = lrelu(latent @ (aw/sqrt(512)).T + abias)*sqrt2 ----
__global__ void style_kernel(const float* __restrict__ latent,
                             const float* __restrict__ aw,
                             const float* __restrict__ abias,
                             float* __restrict__ style) {
    const int b = blockIdx.x;
    const int t = threadIdx.x;              // 256
    __shared__ float lat[512];
    lat[t]       = latent[b * 512 + t];
    lat[t + 256] = latent[b * 512 + t + 256];
    __syncthreads();
    const float wmul = 0.04419417382415922f;  // 1/sqrt(512)
    for (int c = t; c < 512; c += 256) {
        const float* row = aw + (size_t)c * 512;
        float s = 0.f;
        #pragma unroll 8
        for (int k = 0; k < 512; ++k) s += lat[k] * row[k];
        s = s * wmul + abias[c];
        s = (s > 0.f ? s : 0.2f * s) * SQRT2F;
        style[b * 512 + c] = s;
    }
}

// ---------------- kernel 2: raw weights -> bf16 [slab][tap][co][cin32]; demod[b][co] ----
__global__ void wprep_kernel(const float* __restrict__ cw,
                             const float* __restrict__ style,
                             unsigned short* __restrict__ wbf,
                             float* __restrict__ demod) {
    const int co = blockIdx.x;
    const int t = threadIdx.x;              // 256
    __shared__ float raw[4608];
    __shared__ float sty2[8192];
    __shared__ float r2[512];
    const float* row = cw + (size_t)co * 4608;     // [cin][3][3]
    for (int i = t; i < 4608; i += 256) raw[i] = row[i];
    for (int i = t; i < 8192; i += 256) { float v = style[i]; sty2[i] = v * v; }
    __syncthreads();
    for (int cin = t; cin < 512; cin += 256) {
        float s = 0.f;
        #pragma unroll
        for (int tap = 0; tap < 9; ++tap) { float v = raw[cin * 9 + tap]; s += v * v; }
        r2[cin] = s;
    }
    for (int i = t; i < 4608; i += 256) {
        int cin = i / 9, tap = i - cin * 9;
        wbf[(((size_t)(cin >> 5) * 9 + tap) * 512 + co) * 32 + (cin & 31)] = f2bf(raw[i]);
    }
    __syncthreads();
    const int lane = t & 63, wv = t >> 6;
    #pragma unroll
    for (int bb = 0; bb < 4; ++bb) {
        int b = wv * 4 + bb;
        float s = 0.f;
        for (int cin = lane; cin < 512; cin += 64) s += r2[cin] * sty2[b * 512 + cin];
        #pragma unroll
        for (int off = 32; off > 0; off >>= 1) s += __shfl_down(s, off, 64);
        if (lane == 0) demod[b * 512 + co] = rsqrtf(s + 1e-8f);
    }
}

// ---------------- kernel 3: x' = (x + nw*noise)*style[b,cin] -> bf16 padded NHWC-slab ----
// layout: xp[b][slab16][66h][66w][32cin], borders pre-zeroed by memset
__global__ void xprep_kernel(const float* __restrict__ x,
                             const float* __restrict__ noise,
                             const float* __restrict__ nwp,
                             const float* __restrict__ style,
                             unsigned short* __restrict__ xp) {
    const int h = blockIdx.x, slab = blockIdx.y, b = blockIdx.z;
    const int t = threadIdx.x;              // 256
    __shared__ float tile[32][65];
    const int ci4 = t >> 6, w = t & 63;
    const float nv = nwp[0] * noise[(size_t)b * 4096 + h * 64 + w];
    #pragma unroll
    for (int p = 0; p < 8; ++p) {
        int cl = p * 4 + ci4;
        int cin = slab * 32 + cl;
        float v = x[((size_t)(b * 512 + cin)) * 4096 + h * 64 + w];
        tile[cl][w] = (v + nv) * style[b * 512 + cin];
    }
    __syncthreads();
    const int w2 = t >> 2, chunk = t & 3;
    short8 o;
    #pragma unroll
    for (int j = 0; j < 8; ++j) o[j] = (short)f2bf(tile[chunk * 8 + j][w2]);
    *(short8*)(xp + ((size_t)(b * 16 + slab) * 4356 + (h + 1) * 66 + (w2 + 1)) * 32 + chunk * 8) = o;
}

// ---------------- kernel 4: implicit-GEMM conv, async-staged, swizzled LDS ----------------
// 128co x 128pix (8h x 16w) per block; K-loop: 16 cin-slabs x 3 tap-groups of 3.
// LDS rows = 64B (4 chunks of 16B); physical chunk = logical ^ ((row>>1)&3)  -> 2-way free.
__launch_bounds__(256, 2)
__global__ void conv_kernel(const unsigned short* __restrict__ xp,
                            const unsigned short* __restrict__ wbf,
                            const float* __restrict__ demod,
                            const float* __restrict__ bias,
                            float* __restrict__ out) {
    const int b   = blockIdx.z;
    const int co0 = blockIdx.y * 128;
    const int tr  = blockIdx.x >> 2, tc = blockIdx.x & 3;
    const int h0  = tr * 8, w0 = tc * 16;
    const int tid  = threadIdx.x;
    const int lane = tid & 63, wv = tid >> 6;
    const int wr = wv >> 1, wc = wv & 1;
    const int quad = lane >> 4, l16 = lane & 15;

    __shared__ __align__(16) unsigned short lds_x[2][6144];    // 12288B each: 180 pos x 32cin (+pad)
    __shared__ __align__(16) unsigned short lds_w[2][12288];   // 24576B each: 3 taps x 128co x 32cin

    floatx4 acc[4][4] = {};

    // ---- per-thread async staging constants ----
    int wso[6];
    #pragma unroll
    for (int it = 0; it < 6; ++it) {
        int co = (it * 64 + (tid >> 2)) & 127;
        int lchunk = (tid & 3) ^ ((co >> 1) & 3);
        wso[it] = (it >> 1) * 32768 + co * 64 + lchunk * 16;   // bytes: tap_l*32768 + co*64 + chunk*16
    }
    int xo[3];
    #pragma unroll
    for (int it = 0; it < 3; ++it) {
        int pos = it * 64 + (tid >> 2);
        if (pos > 179) pos = 179;                              // dup-load into never-read pad slots
        int r = pos / 18, c = pos - r * 18;
        int lchunk = (tid & 3) ^ ((pos >> 1) & 3);
        xo[it] = (r * 66 + c) * 64 + lchunk * 16;
    }
    const int wvb = wv * 1024;   // wave-uniform LDS byte base within each 4KB it-chunk

    // ---- fragment read offsets (shorts) ----
    int a_off[4];
    #pragma unroll
    for (int mi = 0; mi < 4; ++mi) {
        int co = wr * 64 + mi * 16 + l16;
        a_off[mi] = co * 32 + (quad ^ ((co >> 1) & 3)) * 8;
    }
    int bo[4][9];
    #pragma unroll
    for (int ni = 0; ni < 4; ++ni)
        #pragma unroll
        for (int kh = 0; kh < 3; ++kh)
            #pragma unroll
            for (int kw = 0; kw < 3; ++kw) {
                int pos = (wc * 4 + ni + kh) * 18 + kw + l16;
                bo[ni][kh * 3 + kw] = pos * 32 + (quad ^ ((pos >> 1) & 3)) * 8;
            }

    const char* xpb = (const char*)xp + ((size_t)b * 16 * 4356 + h0 * 66 + w0) * 64;
    const char* wb0 = (const char*)wbf + (size_t)co0 * 64;   // FIX: include co block offset

    // ---- prologue: slab0 x-tile + group0 weights into buffer 0 ----
    #pragma unroll
    for (int it = 0; it < 3; ++it)
        gl_lds16(xpb + xo[it], (char*)lds_x[0] + it * 4096 + wvb);
    #pragma unroll
    for (int it = 0; it < 6; ++it)
        gl_lds16(wb0 + wso[it], (char*)lds_w[0] + it * 4096 + wvb);

    for (int s = 0; s < 16; ++s) {
        #pragma unroll
        for (int g = 0; g < 3; ++g) {
            __syncthreads();   // drains async loads for (s,g)
            // prefetch next weight group (and next slab's x-tile during g==0)
            if (g < 2) {
                const char* gw = wb0 + s * 294912 + (g + 1) * 98304;
                char* lw = (char*)lds_w[(s + g + 1) & 1];
                #pragma unroll
                for (int it = 0; it < 6; ++it)
                    gl_lds16(gw + wso[it], lw + it * 4096 + wvb);
            } else if (s < 15) {
                const char* gw = wb0 + (s + 1) * 294912;
                char* lw = (char*)lds_w[(s + 1) & 1];
                #pragma unroll
                for (int it = 0; it < 6; ++it)
                    gl_lds16(gw + wso[it], lw + it * 4096 + wvb);
            }
            if (g == 0 && s < 15) {
                const char* gx = xpb + (size_t)(s + 1) * 278784;
                char* lx = (char*)lds_x[(s + 1) & 1];
                #pragma unroll
                for (int it = 0; it < 3; ++it)
                    gl_lds16(gx + xo[it], lx + it * 4096 + wvb);
            }
            // compute: 3 taps x 16 MFMA per wave
            const unsigned short* wbuf = lds_w[(s + g) & 1];
            const unsigned short* xbuf = lds_x[s & 1];
            #pragma unroll
            for (int tl = 0; tl < 3; ++tl) {
                const int tap = g * 3 + tl;
                short8 a[4], bb[4];
                #pragma unroll
                for (int mi = 0; mi < 4; ++mi)
                    a[mi] = *(const short8*)(wbuf + tl * 4096 + a_off[mi]);
                #pragma unroll
                for (int ni = 0; ni < 4; ++ni)
                    bb[ni] = *(const short8*)(xbuf + bo[ni][tap]);
                #pragma unroll
                for (int mi = 0; mi < 4; ++mi)
                    #pragma unroll
                    for (int ni = 0; ni < 4; ++ni)
                        acc[mi][ni] = __builtin_amdgcn_mfma_f32_16x16x32_bf16(
                            a[mi], bb[ni], acc[mi][ni], 0, 0, 0);
            }
        }
    }

    // ---- epilogue: *demod + bias, leaky_relu*sqrt2 ----
    const float* dmb = demod + b * 512;
    #pragma unroll
    for (int mi = 0; mi < 4; ++mi) {
        const int cob = co0 + wr * 64 + mi * 16 + quad * 4;
        float bv[4], dv[4];
        #pragma unroll
        for (int i = 0; i < 4; ++i) { bv[i] = bias[cob + i]; dv[i] = dmb[cob + i]; }
        #pragma unroll
        for (int ni = 0; ni < 4; ++ni) {
            const int gh = h0 + wc * 4 + ni;
            const int gw = w0 + l16;
            #pragma unroll
            for (int i = 0; i < 4; ++i) {
                float v = acc[mi][ni][i] * dv[i] + bv[i];
                v = (v > 0.f ? v : 0.2f * v) * SQRT2F;
                out[(((size_t)b * 512 + cob + i) * 64 + gh) * 64 + gw] = v;
            }
        }
    }
}

extern "C" void kernel_launch(void* const* d_in, const int* in_sizes, int n_in,
                              void* d_out, int out_size, void* d_ws, size_t ws_size,
                              hipStream_t stream) {
    const float* x      = (const float*)d_in[0];
    const float* latent = (const float*)d_in[1];
    const float* noise  = (const float*)d_in[2];
    const float* aw     = (const float*)d_in[3];
    const float* abias  = (const float*)d_in[4];
    const float* cw     = (const float*)d_in[5];
    const float* nwp    = (const float*)d_in[6];
    const float* bias   = (const float*)d_in[7];
    float* out = (float*)d_out;

    float* style         = (float*)d_ws;                                      // 32 KB
    float* demod         = (float*)((char*)d_ws + 32768);                     // 32 KB
    unsigned short* wbf  = (unsigned short*)((char*)d_ws + 65536);            // 4.72 MB
    unsigned short* xp   = (unsigned short*)((char*)d_ws + 65536 + 4718592);  // 71.4 MB

    hipMemsetAsync(xp, 0, (size_t)16 * 16 * 4356 * 64, stream);   // zero halo borders
    style_kernel<<<dim3(16), dim3(256), 0, stream>>>(latent, aw, abias, style);
    wprep_kernel<<<dim3(512), dim3(256), 0, stream>>>(cw, style, wbf, demod);
    xprep_kernel<<<dim3(64, 16, 16), dim3(256), 0, stream>>>(x, noise, nwp, style, xp);
    conv_kernel<<<dim3(32, 4, 16), dim3(256), 0, stream>>>(xp, wbf, demod, bias, out);
}